// Round 1
// baseline (1678.648 us; speedup 1.0000x reference)
//
#include <hip/hip_runtime.h>
#include <stdint.h>

typedef unsigned short u16;
typedef __attribute__((ext_vector_type(4))) float f32x4;
typedef __attribute__((ext_vector_type(8))) __bf16 bf16x8;
typedef __attribute__((ext_vector_type(4))) u16 u16x4;

#define B_  8192
#define D_  4096
#define C4_ 4096
#define C_  1024
#define K_  8192
#define BM  128
#define BN  128

__device__ __forceinline__ void load_lds16(const void* g, void* l) {
  __builtin_amdgcn_global_load_lds(
      (const __attribute__((address_space(1))) unsigned int*)g,
      (__attribute__((address_space(3))) unsigned int*)l, 16, 0, 0);
}

__device__ __forceinline__ u16 f2bf(float v) {
  unsigned int u = __float_as_uint(v);
  return (u16)((u + 0x7FFFu + ((u >> 16) & 1u)) >> 16);   // RNE
}
__device__ __forceinline__ float bf2f(u16 u) {
  return __uint_as_float(((unsigned int)u) << 16);
}
__device__ __forceinline__ unsigned int fkey(float x) {   // monotone float->uint
  unsigned int u = __float_as_uint(x);
  return u ^ (((unsigned int)(((int)u) >> 31)) | 0x80000000u);
}

// ---------------- split-bf16 GEMM mainloop (m97 structure) -----------------
// A: [M][K] hi/lo bf16 row-major (K contiguous). B: [N][K] hi/lo bf16 (B^T).
// 128x128 tile, BK=64, 256 threads = 4 waves (2x2), 4x4 16x16 frags/wave.
// acc = Ah*Bh + Al*Bh + Ah*Bl  (~17-bit effective input mantissa).
__device__ __forceinline__ void mfma_mainloop(
    const u16* __restrict__ Ah, const u16* __restrict__ Al,
    const u16* __restrict__ Bh, const u16* __restrict__ Bl,
    int K, int rowA0, int rowB0, u16* lds, f32x4 acc[4][4]) {
  const int tid = threadIdx.x;
  const int lane = tid & 63;
  const int w = tid >> 6;
  const int wr = w >> 1, wc = w & 1;

  u16* As_h = lds;            // [128][64]
  u16* As_l = lds + 8192;
  u16* Bs_h = lds + 16384;
  u16* Bs_l = lds + 24576;

#pragma unroll
  for (int m = 0; m < 4; ++m)
#pragma unroll
    for (int n = 0; n < 4; ++n) acc[m][n] = (f32x4){0.f, 0.f, 0.f, 0.f};

  const int rstage = w * 8 + (lane >> 3);   // row within 32-row stage chunk
  const int estage = (lane & 7) * 8;        // bf16-element offset (16B/lane)

  for (int k0 = 0; k0 < K; k0 += 64) {
#pragma unroll
    for (int c = 0; c < 4; ++c) {
      const int r = c * 32 + rstage;
      const size_t ga = (size_t)(rowA0 + r) * K + (k0 + estage);
      const size_t gb = (size_t)(rowB0 + r) * K + (k0 + estage);
      const int lo = (c * 32 + w * 8) * 64;  // wave-uniform LDS base
      load_lds16(Ah + ga, As_h + lo);
      load_lds16(Al + ga, As_l + lo);
      load_lds16(Bh + gb, Bs_h + lo);
      load_lds16(Bl + gb, Bs_l + lo);
    }
    __syncthreads();
#pragma unroll
    for (int ks = 0; ks < 2; ++ks) {
      bf16x8 ah[4], al[4], bh[4], bl[4];
      const int kof = ks * 32 + (lane >> 4) * 8;
#pragma unroll
      for (int m = 0; m < 4; ++m) {
        const int ra = (wr * 64 + m * 16 + (lane & 15)) * 64 + kof;
        ah[m] = *(const bf16x8*)(As_h + ra);
        al[m] = *(const bf16x8*)(As_l + ra);
      }
#pragma unroll
      for (int n = 0; n < 4; ++n) {
        const int rb = (wc * 64 + n * 16 + (lane & 15)) * 64 + kof;
        bh[n] = *(const bf16x8*)(Bs_h + rb);
        bl[n] = *(const bf16x8*)(Bs_l + rb);
      }
#pragma unroll
      for (int m = 0; m < 4; ++m)
#pragma unroll
        for (int n = 0; n < 4; ++n) {
          acc[m][n] = __builtin_amdgcn_mfma_f32_16x16x32_bf16(ah[m], bh[n], acc[m][n], 0, 0, 0);
          acc[m][n] = __builtin_amdgcn_mfma_f32_16x16x32_bf16(al[m], bh[n], acc[m][n], 0, 0, 0);
          acc[m][n] = __builtin_amdgcn_mfma_f32_16x16x32_bf16(ah[m], bl[n], acc[m][n], 0, 0, 0);
        }
    }
    __syncthreads();
  }
}

// -------- GEMM1: h = silu(x@W1 + b1), write h as bf16 hi/lo ---------------
__global__ __launch_bounds__(256, 2)
void k_gemm1(const u16* __restrict__ xh, const u16* __restrict__ xl,
             const u16* __restrict__ w1h, const u16* __restrict__ w1l,
             const float* __restrict__ b1,
             u16* __restrict__ hh, u16* __restrict__ hl) {
  __shared__ u16 lds[32768];
  const int nbn = C4_ / BN;
  const int bm = blockIdx.x / nbn, bn = blockIdx.x % nbn;
  f32x4 acc[4][4];
  mfma_mainloop(xh, xl, w1h, w1l, D_, bm * BM, bn * BN, lds, acc);
  const int lane = threadIdx.x & 63, w = threadIdx.x >> 6;
  const int wr = w >> 1, wc = w & 1;
#pragma unroll
  for (int m = 0; m < 4; ++m)
#pragma unroll
    for (int n = 0; n < 4; ++n)
#pragma unroll
      for (int j = 0; j < 4; ++j) {
        const int rg = bm * BM + wr * 64 + m * 16 + (lane >> 4) * 4 + j;
        const int cg = bn * BN + wc * 64 + n * 16 + (lane & 15);
        const float v = acc[m][n][j] + b1[cg];
        const float s = v / (1.f + __expf(-v));
        const size_t o = (size_t)rg * C4_ + cg;
        const u16 hi = f2bf(s);
        hh[o] = hi;
        hl[o] = f2bf(s - bf2f(hi));
      }
}

// -------- GEMM2: z = h@W2 + b2, write z f32 + bf16 hi/lo ------------------
__global__ __launch_bounds__(256, 2)
void k_gemm2(const u16* __restrict__ ah, const u16* __restrict__ al,
             const u16* __restrict__ bh, const u16* __restrict__ bl,
             const float* __restrict__ b2,
             float* __restrict__ zf, u16* __restrict__ zh, u16* __restrict__ zl) {
  __shared__ u16 lds[32768];
  const int nbn = C_ / BN;
  const int bm = blockIdx.x / nbn, bn = blockIdx.x % nbn;
  f32x4 acc[4][4];
  mfma_mainloop(ah, al, bh, bl, C4_, bm * BM, bn * BN, lds, acc);
  const int lane = threadIdx.x & 63, w = threadIdx.x >> 6;
  const int wr = w >> 1, wc = w & 1;
#pragma unroll
  for (int m = 0; m < 4; ++m)
#pragma unroll
    for (int n = 0; n < 4; ++n)
#pragma unroll
      for (int j = 0; j < 4; ++j) {
        const int rg = bm * BM + wr * 64 + m * 16 + (lane >> 4) * 4 + j;
        const int cg = bn * BN + wc * 64 + n * 16 + (lane & 15);
        const float v = acc[m][n][j] + b2[cg];
        const size_t o = (size_t)rg * C_ + cg;
        zf[o] = v;
        const u16 hi = f2bf(v);
        zh[o] = hi;
        zl[o] = f2bf(v - bf2f(hi));
      }
}

// -------- GEMM3: s = ||e_k||^2 - 2 z.e_k, fused row-argmin ----------------
__global__ __launch_bounds__(256, 2)
void k_gemm3(const u16* __restrict__ zh, const u16* __restrict__ zl,
             const u16* __restrict__ eh, const u16* __restrict__ el,
             const float* __restrict__ norms, unsigned long long* __restrict__ am) {
  __shared__ u16 lds[32768];
  const int nbn = K_ / BN;
  const int bm = blockIdx.x / nbn, bn = blockIdx.x % nbn;
  f32x4 acc[4][4];
  mfma_mainloop(zh, zl, eh, el, C_, bm * BM, bn * BN, lds, acc);
  const int lane = threadIdx.x & 63, w = threadIdx.x >> 6;
  const int wr = w >> 1, wc = w & 1;
#pragma unroll
  for (int m = 0; m < 4; ++m) {
#pragma unroll
    for (int j = 0; j < 4; ++j) {
      float best = 3.4e38f;
      int bestn = 0x7fffffff;
#pragma unroll
      for (int n = 0; n < 4; ++n) {
        const int cg = bn * BN + wc * 64 + n * 16 + (lane & 15);
        const float s = norms[cg] - 2.f * acc[m][n][j];
        if (s < best) { best = s; bestn = cg; }
      }
      // reduce across the 16 lanes (lane&15) holding this row
#pragma unroll
      for (int off = 1; off <= 8; off <<= 1) {
        const float ob = __shfl_xor(best, off, 64);
        const int obn = __shfl_xor(bestn, off, 64);
        if (ob < best || (ob == best && obn < bestn)) { best = ob; bestn = obn; }
      }
      if ((lane & 15) == 0) {
        const int rg = bm * BM + wr * 64 + m * 16 + (lane >> 4) * 4 + j;
        const unsigned long long key =
            ((unsigned long long)fkey(best) << 32) | (unsigned int)bestn;
        atomicMin(&am[rg], key);
      }
    }
  }
}

// -------- prep kernels ----------------------------------------------------
__global__ void k_split(const float4* __restrict__ in, size_t n4,
                        u16* __restrict__ hi, u16* __restrict__ lo) {
  size_t i = (size_t)blockIdx.x * blockDim.x + threadIdx.x;
  const size_t stride = (size_t)gridDim.x * blockDim.x;
  for (; i < n4; i += stride) {
    const float4 v = in[i];
    const float vv[4] = {v.x, v.y, v.z, v.w};
    u16x4 h, l;
#pragma unroll
    for (int j = 0; j < 4; ++j) {
      const u16 a = f2bf(vv[j]);
      h[j] = a;
      l[j] = f2bf(vv[j] - bf2f(a));
    }
    *(u16x4*)(hi + i * 4) = h;
    *(u16x4*)(lo + i * 4) = l;
  }
}

template <bool WF32>
__global__ void k_tsplit(const float* __restrict__ in, int R, int Cc,
                         u16* __restrict__ hiT, u16* __restrict__ loT,
                         float* __restrict__ f32T) {
  __shared__ float t[32][33];
  const int c0 = blockIdx.x * 32, r0 = blockIdx.y * 32;
  const int tx = threadIdx.x, ty = threadIdx.y;
#pragma unroll
  for (int i = 0; i < 4; ++i)
    t[ty + i * 8][tx] = in[(size_t)(r0 + ty + i * 8) * Cc + (c0 + tx)];
  __syncthreads();
#pragma unroll
  for (int i = 0; i < 4; ++i) {
    const int orow = c0 + ty + i * 8;
    const int ocol = r0 + tx;
    const float v = t[tx][ty + i * 8];
    const size_t o = (size_t)orow * R + ocol;
    const u16 hi = f2bf(v);
    hiT[o] = hi;
    loT[o] = f2bf(v - bf2f(hi));
    if (WF32) f32T[o] = v;
  }
}

__global__ void k_norms(const float* __restrict__ embed, float* __restrict__ norms) {
  const int k = blockIdx.x * blockDim.x + threadIdx.x;
  if (k >= K_) return;
  double s = 0.0;
  for (int c = 0; c < C_; ++c) {
    const float v = embed[(size_t)c * K_ + k];
    s += (double)v * (double)v;
  }
  norms[k] = (float)s;
}

__global__ void k_init(unsigned long long* __restrict__ am, double* __restrict__ dacc) {
  const int i = blockIdx.x * blockDim.x + threadIdx.x;
  if (i < B_) am[i] = 0xFFFFFFFFFFFFFFFFull;
  if (i == 0) *dacc = 0.0;
}

// -------- finalize: gather + LayerNorm + commitment partial ---------------
__global__ __launch_bounds__(256)
void k_finalize(const unsigned long long* __restrict__ am,
                const float* __restrict__ embT, const float* __restrict__ zf,
                const float* __restrict__ gamma, const float* __restrict__ beta,
                float* __restrict__ out, double* __restrict__ dacc) {
  const int row = blockIdx.x;
  const int tid = threadIdx.x;
  const int lane = tid & 63, w = tid >> 6;
  const int idx = (int)(am[row] & 0xFFFFFFFFull);

  const float4 e4 = *(const float4*)(embT + (size_t)idx * C_ + tid * 4);
  float s1 = e4.x + e4.y + e4.z + e4.w;
  float s2 = e4.x * e4.x + e4.y * e4.y + e4.z * e4.z + e4.w * e4.w;
#pragma unroll
  for (int off = 32; off >= 1; off >>= 1) {
    s1 += __shfl_xor(s1, off, 64);
    s2 += __shfl_xor(s2, off, 64);
  }
  __shared__ float r1[4], r2[4], rd[4];
  if (lane == 0) { r1[w] = s1; r2[w] = s2; }
  __syncthreads();
  const float S1 = r1[0] + r1[1] + r1[2] + r1[3];
  const float S2 = r2[0] + r2[1] + r2[2] + r2[3];
  const float mu = S1 * (1.f / C_);
  const float var = S2 * (1.f / C_) - mu * mu;
  const float inv = 1.f / sqrtf(var + 1e-5f);

  const float4 z4 = *(const float4*)(zf + (size_t)row * C_ + tid * 4);
  const float4 g4 = *(const float4*)(gamma + tid * 4);
  const float4 b4 = *(const float4*)(beta + tid * 4);
  float4 o4;
  o4.x = (e4.x - mu) * inv * g4.x + b4.x;
  o4.y = (e4.y - mu) * inv * g4.y + b4.y;
  o4.z = (e4.z - mu) * inv * g4.z + b4.z;
  o4.w = (e4.w - mu) * inv * g4.w + b4.w;
  *(float4*)(out + (size_t)row * C_ + tid * 4) = o4;

  const float dx = e4.x - z4.x, dy = e4.y - z4.y, dz = e4.z - z4.z, dw = e4.w - z4.w;
  float d = dx * dx + dy * dy + dz * dz + dw * dw;
#pragma unroll
  for (int off = 32; off >= 1; off >>= 1) d += __shfl_xor(d, off, 64);
  __syncthreads();
  if (lane == 0) rd[w] = d;
  __syncthreads();
  if (tid == 0) atomicAdd(dacc, (double)(rd[0] + rd[1] + rd[2] + rd[3]));
}

__global__ void k_wdiff(const double* __restrict__ dacc, float* __restrict__ out) {
  out[(size_t)B_ * C_] = (float)(0.01 * (*dacc) / ((double)B_ * (double)C_));
}

// ---------------------------------------------------------------------------
extern "C" void kernel_launch(void* const* d_in, const int* in_sizes, int n_in,
                              void* d_out, int out_size, void* d_ws, size_t ws_size,
                              hipStream_t stream) {
  const float* x     = (const float*)d_in[0];
  const float* W1    = (const float*)d_in[1];
  const float* b1    = (const float*)d_in[2];
  const float* W2    = (const float*)d_in[3];
  const float* b2    = (const float*)d_in[4];
  const float* gamma = (const float*)d_in[5];
  const float* beta  = (const float*)d_in[6];
  const float* embed = (const float*)d_in[7];
  float* out = (float*)d_out;

  char* ws = (char*)d_ws;
  const size_t MB64 = 67108864ull;  // 8192*4096*2
  // region A [0,64M): x_hi  -> later W2T_hi/lo + z_f32
  // region B [64M,128M): x_lo -> later z_hi/z_lo + norms + am + dacc
  // region C [128M,160M): W1T_hi -> later embT f32 (exact fit with D)
  // region D [160M,192M): W1T_lo -> later embT hi/lo
  // region E [192M,256M): h_hi ; region F [256M,320M): h_lo
  u16* xh  = (u16*)(ws);
  u16* xl  = (u16*)(ws + MB64);
  u16* w1h = (u16*)(ws + 2 * MB64);
  u16* w1l = (u16*)(ws + 2 * MB64 + 33554432ull);
  u16* hh  = (u16*)(ws + 3 * MB64);
  u16* hl  = (u16*)(ws + 4 * MB64);
  u16* w2h = (u16*)(ws);
  u16* w2l = (u16*)(ws + 8388608ull);
  float* zf = (float*)(ws + 16777216ull);
  u16* zh  = (u16*)(ws + MB64);
  u16* zl  = (u16*)(ws + MB64 + 16777216ull);
  float* norms = (float*)(ws + MB64 + 33554432ull);
  unsigned long long* am = (unsigned long long*)(ws + MB64 + 33554432ull + 65536ull);
  double* dacc = (double*)(ws + MB64 + 33554432ull + 131072ull);
  float* embT = (float*)(ws + 2 * MB64);
  u16* eh  = (u16*)(ws + 2 * MB64 + 33554432ull);
  u16* el  = (u16*)(ws + 2 * MB64 + 50331648ull);

  // 1. split x -> xh/xl
  k_split<<<2048, 256, 0, stream>>>((const float4*)x, (size_t)B_ * D_ / 4, xh, xl);
  // 2. W1 [D][4C] -> W1T hi/lo [4C][D]
  k_tsplit<false><<<dim3(C4_ / 32, D_ / 32), dim3(32, 8), 0, stream>>>(W1, D_, C4_, w1h, w1l, nullptr);
  // 3. GEMM1 (+bias+SiLU+split)
  k_gemm1<<<(B_ / BM) * (C4_ / BN), 256, 0, stream>>>(xh, xl, w1h, w1l, b1, hh, hl);
  // 4. W2 [4C][C] -> W2T hi/lo [C][4C]  (region A is free now)
  k_tsplit<false><<<dim3(C_ / 32, C4_ / 32), dim3(32, 8), 0, stream>>>(W2, C4_, C_, w2h, w2l, nullptr);
  // 5. GEMM2 (+bias, write z f32 + hi/lo)
  k_gemm2<<<(B_ / BM) * (C_ / BN), 256, 0, stream>>>(hh, hl, w2h, w2l, b2, zf, zh, zl);
  // 6. embed [C][K] -> embT f32 + hi/lo [K][C]  (regions C/D free now)
  k_tsplit<true><<<dim3(K_ / 32, C_ / 32), dim3(32, 8), 0, stream>>>(embed, C_, K_, eh, el, embT);
  // 7. codebook column norms (f64 accumulate)
  k_norms<<<K_ / 256, 256, 0, stream>>>(embed, norms);
  // 8. init argmin keys + diff accumulator
  k_init<<<B_ / 256, 256, 0, stream>>>(am, dacc);
  // 9. GEMM3 + fused argmin
  k_gemm3<<<(B_ / BM) * (K_ / BN), 256, 0, stream>>>(zh, zl, eh, el, norms, am);
  // 10. gather + LayerNorm + commitment partial sums
  k_finalize<<<B_, 256, 0, stream>>>(am, embT, zf, gamma, beta, out, dacc);
  // 11. scalar diff output
  k_wdiff<<<1, 1, 0, stream>>>(dacc, out);
}

// Round 2
// 1508.258 us; speedup vs baseline: 1.1130x; 1.1130x over previous
//
#include <hip/hip_runtime.h>
#include <stdint.h>

typedef unsigned short u16;
typedef __attribute__((ext_vector_type(4))) float f32x4;
typedef __attribute__((ext_vector_type(8))) __bf16 bf16x8;
typedef __attribute__((ext_vector_type(4))) u16 u16x4;

#define B_  8192
#define D_  4096
#define C4_ 4096
#define C_  1024
#define K_  8192
#define BM  128
#define BN  128

__device__ __forceinline__ void load_lds16(const void* g, void* l) {
  __builtin_amdgcn_global_load_lds(
      (const __attribute__((address_space(1))) unsigned int*)g,
      (__attribute__((address_space(3))) unsigned int*)l, 16, 0, 0);
}

__device__ __forceinline__ u16 f2bf(float v) {
  unsigned int u = __float_as_uint(v);
  return (u16)((u + 0x7FFFu + ((u >> 16) & 1u)) >> 16);   // RNE
}
__device__ __forceinline__ float bf2f(u16 u) {
  return __uint_as_float(((unsigned int)u) << 16);
}
__device__ __forceinline__ unsigned int fkey(float x) {   // monotone float->uint
  unsigned int u = __float_as_uint(x);
  return u ^ (((unsigned int)(((int)u) >> 31)) | 0x80000000u);
}

// ---------------- split-bf16 GEMM mainloop (m97 structure + T2 swizzle) ----
// A: [M][K] hi/lo bf16 row-major (K contiguous). B: [N][K] hi/lo bf16 (B^T).
// 128x128 tile, BK=64, 256 threads = 4 waves (2x2), 4x4 16x16 frags/wave.
// acc = Ah*Bh + Al*Bh + Ah*Bl  (~17-bit effective input mantissa).
// LDS rows are 64 bf16 = 128 B = exactly 32 banks, so unswizzled fragment
// reads are ~16-way bank conflicts. Fix (rule #21, both sides): the 16B slot
// s within a row holds global slot s ^ (row&7). Staging pre-swizzles the
// GLOBAL lane address (LDS dest stays linear for global_load_lds); reads
// apply the same XOR.
__device__ __forceinline__ void mfma_mainloop(
    const u16* __restrict__ Ah, const u16* __restrict__ Al,
    const u16* __restrict__ Bh, const u16* __restrict__ Bl,
    int K, int rowA0, int rowB0, u16* lds, f32x4 acc[4][4]) {
  const int tid = threadIdx.x;
  const int lane = tid & 63;
  const int w = tid >> 6;
  const int wr = w >> 1, wc = w & 1;

  u16* As_h = lds;            // [128][64]
  u16* As_l = lds + 8192;
  u16* Bs_h = lds + 16384;
  u16* Bs_l = lds + 24576;

#pragma unroll
  for (int m = 0; m < 4; ++m)
#pragma unroll
    for (int n = 0; n < 4; ++n) acc[m][n] = (f32x4){0.f, 0.f, 0.f, 0.f};

  const int rstage = w * 8 + (lane >> 3);   // row within 32-row stage chunk
  // pre-swizzled global 16B-slot: lane loads slot (lane&7)^(row&7), so that
  // LDS[row][slot s] = global slot s^(row&7). row&7 == lane>>3 here.
  const int estage = (((lane & 7) ^ (lane >> 3)) << 3);

  for (int k0 = 0; k0 < K; k0 += 64) {
#pragma unroll
    for (int c = 0; c < 4; ++c) {
      const int r = c * 32 + rstage;
      const size_t ga = (size_t)(rowA0 + r) * K + (k0 + estage);
      const size_t gb = (size_t)(rowB0 + r) * K + (k0 + estage);
      const int lo = (c * 32 + w * 8) * 64;  // wave-uniform LDS base
      load_lds16(Ah + ga, As_h + lo);
      load_lds16(Al + ga, As_l + lo);
      load_lds16(Bh + gb, Bs_h + lo);
      load_lds16(Bl + gb, Bs_l + lo);
    }
    __syncthreads();
#pragma unroll
    for (int ks = 0; ks < 2; ++ks) {
      bf16x8 ah[4], al[4], bh[4], bl[4];
      // fragment rows are wr*64 + m*16 + (lane&15): row&7 == lane&7 for all
      // m, so the swizzled 16B slot is (ks*4 + (lane>>4)) ^ (lane&7).
      const int kof = (((ks * 4 + (lane >> 4)) ^ (lane & 7)) << 3);
#pragma unroll
      for (int m = 0; m < 4; ++m) {
        const int ra = (wr * 64 + m * 16 + (lane & 15)) * 64 + kof;
        ah[m] = *(const bf16x8*)(As_h + ra);
        al[m] = *(const bf16x8*)(As_l + ra);
      }
#pragma unroll
      for (int n = 0; n < 4; ++n) {
        const int rb = (wc * 64 + n * 16 + (lane & 15)) * 64 + kof;
        bh[n] = *(const bf16x8*)(Bs_h + rb);
        bl[n] = *(const bf16x8*)(Bs_l + rb);
      }
#pragma unroll
      for (int m = 0; m < 4; ++m)
#pragma unroll
        for (int n = 0; n < 4; ++n) {
          acc[m][n] = __builtin_amdgcn_mfma_f32_16x16x32_bf16(ah[m], bh[n], acc[m][n], 0, 0, 0);
          acc[m][n] = __builtin_amdgcn_mfma_f32_16x16x32_bf16(al[m], bh[n], acc[m][n], 0, 0, 0);
          acc[m][n] = __builtin_amdgcn_mfma_f32_16x16x32_bf16(ah[m], bl[n], acc[m][n], 0, 0, 0);
        }
    }
    __syncthreads();
  }
}

// -------- GEMM1: h = silu(x@W1 + b1), write h as bf16 hi/lo ---------------
__global__ __launch_bounds__(256, 2)
void k_gemm1(const u16* __restrict__ xh, const u16* __restrict__ xl,
             const u16* __restrict__ w1h, const u16* __restrict__ w1l,
             const float* __restrict__ b1,
             u16* __restrict__ hh, u16* __restrict__ hl) {
  __shared__ u16 lds[32768];
  const int nbn = C4_ / BN;
  const int bm = blockIdx.x / nbn, bn = blockIdx.x % nbn;
  f32x4 acc[4][4];
  mfma_mainloop(xh, xl, w1h, w1l, D_, bm * BM, bn * BN, lds, acc);
  const int lane = threadIdx.x & 63, w = threadIdx.x >> 6;
  const int wr = w >> 1, wc = w & 1;
#pragma unroll
  for (int m = 0; m < 4; ++m)
#pragma unroll
    for (int n = 0; n < 4; ++n)
#pragma unroll
      for (int j = 0; j < 4; ++j) {
        const int rg = bm * BM + wr * 64 + m * 16 + (lane >> 4) * 4 + j;
        const int cg = bn * BN + wc * 64 + n * 16 + (lane & 15);
        const float v = acc[m][n][j] + b1[cg];
        const float s = v / (1.f + __expf(-v));
        const size_t o = (size_t)rg * C4_ + cg;
        const u16 hi = f2bf(s);
        hh[o] = hi;
        hl[o] = f2bf(s - bf2f(hi));
      }
}

// -------- GEMM2: z = h@W2 + b2, write z f32 + bf16 hi/lo ------------------
__global__ __launch_bounds__(256, 2)
void k_gemm2(const u16* __restrict__ ah, const u16* __restrict__ al,
             const u16* __restrict__ bh, const u16* __restrict__ bl,
             const float* __restrict__ b2,
             float* __restrict__ zf, u16* __restrict__ zh, u16* __restrict__ zl) {
  __shared__ u16 lds[32768];
  const int nbn = C_ / BN;
  const int bm = blockIdx.x / nbn, bn = blockIdx.x % nbn;
  f32x4 acc[4][4];
  mfma_mainloop(ah, al, bh, bl, C4_, bm * BM, bn * BN, lds, acc);
  const int lane = threadIdx.x & 63, w = threadIdx.x >> 6;
  const int wr = w >> 1, wc = w & 1;
#pragma unroll
  for (int m = 0; m < 4; ++m)
#pragma unroll
    for (int n = 0; n < 4; ++n)
#pragma unroll
      for (int j = 0; j < 4; ++j) {
        const int rg = bm * BM + wr * 64 + m * 16 + (lane >> 4) * 4 + j;
        const int cg = bn * BN + wc * 64 + n * 16 + (lane & 15);
        const float v = acc[m][n][j] + b2[cg];
        const size_t o = (size_t)rg * C_ + cg;
        zf[o] = v;
        const u16 hi = f2bf(v);
        zh[o] = hi;
        zl[o] = f2bf(v - bf2f(hi));
      }
}

// -------- GEMM3: s = ||e_k||^2 - 2 z.e_k, fused row-argmin ----------------
__global__ __launch_bounds__(256, 2)
void k_gemm3(const u16* __restrict__ zh, const u16* __restrict__ zl,
             const u16* __restrict__ eh, const u16* __restrict__ el,
             const float* __restrict__ norms, unsigned long long* __restrict__ am) {
  __shared__ u16 lds[32768];
  const int nbn = K_ / BN;
  const int bm = blockIdx.x / nbn, bn = blockIdx.x % nbn;
  f32x4 acc[4][4];
  mfma_mainloop(zh, zl, eh, el, C_, bm * BM, bn * BN, lds, acc);
  const int lane = threadIdx.x & 63, w = threadIdx.x >> 6;
  const int wr = w >> 1, wc = w & 1;
#pragma unroll
  for (int m = 0; m < 4; ++m) {
#pragma unroll
    for (int j = 0; j < 4; ++j) {
      float best = 3.4e38f;
      int bestn = 0x7fffffff;
#pragma unroll
      for (int n = 0; n < 4; ++n) {
        const int cg = bn * BN + wc * 64 + n * 16 + (lane & 15);
        const float s = norms[cg] - 2.f * acc[m][n][j];
        if (s < best) { best = s; bestn = cg; }
      }
      // reduce across the 16 lanes (lane&15) holding this row
#pragma unroll
      for (int off = 1; off <= 8; off <<= 1) {
        const float ob = __shfl_xor(best, off, 64);
        const int obn = __shfl_xor(bestn, off, 64);
        if (ob < best || (ob == best && obn < bestn)) { best = ob; bestn = obn; }
      }
      if ((lane & 15) == 0) {
        const int rg = bm * BM + wr * 64 + m * 16 + (lane >> 4) * 4 + j;
        const unsigned long long key =
            ((unsigned long long)fkey(best) << 32) | (unsigned int)bestn;
        atomicMin(&am[rg], key);
      }
    }
  }
}

// -------- prep kernels ----------------------------------------------------
__global__ void k_split(const float4* __restrict__ in, size_t n4,
                        u16* __restrict__ hi, u16* __restrict__ lo) {
  size_t i = (size_t)blockIdx.x * blockDim.x + threadIdx.x;
  const size_t stride = (size_t)gridDim.x * blockDim.x;
  for (; i < n4; i += stride) {
    const float4 v = in[i];
    const float vv[4] = {v.x, v.y, v.z, v.w};
    u16x4 h, l;
#pragma unroll
    for (int j = 0; j < 4; ++j) {
      const u16 a = f2bf(vv[j]);
      h[j] = a;
      l[j] = f2bf(vv[j] - bf2f(a));
    }
    *(u16x4*)(hi + i * 4) = h;
    *(u16x4*)(lo + i * 4) = l;
  }
}

template <bool WF32>
__global__ void k_tsplit(const float* __restrict__ in, int R, int Cc,
                         u16* __restrict__ hiT, u16* __restrict__ loT,
                         float* __restrict__ f32T) {
  __shared__ float t[32][33];
  const int c0 = blockIdx.x * 32, r0 = blockIdx.y * 32;
  const int tx = threadIdx.x, ty = threadIdx.y;
#pragma unroll
  for (int i = 0; i < 4; ++i)
    t[ty + i * 8][tx] = in[(size_t)(r0 + ty + i * 8) * Cc + (c0 + tx)];
  __syncthreads();
#pragma unroll
  for (int i = 0; i < 4; ++i) {
    const int orow = c0 + ty + i * 8;
    const int ocol = r0 + tx;
    const float v = t[tx][ty + i * 8];
    const size_t o = (size_t)orow * R + ocol;
    const u16 hi = f2bf(v);
    hiT[o] = hi;
    loT[o] = f2bf(v - bf2f(hi));
    if (WF32) f32T[o] = v;
  }
}

__global__ void k_norms(const float* __restrict__ embed, float* __restrict__ norms) {
  const int k = blockIdx.x * blockDim.x + threadIdx.x;
  if (k >= K_) return;
  double s = 0.0;
  for (int c = 0; c < C_; ++c) {
    const float v = embed[(size_t)c * K_ + k];
    s += (double)v * (double)v;
  }
  norms[k] = (float)s;
}

__global__ void k_init(unsigned long long* __restrict__ am, double* __restrict__ dacc) {
  const int i = blockIdx.x * blockDim.x + threadIdx.x;
  if (i < B_) am[i] = 0xFFFFFFFFFFFFFFFFull;
  if (i == 0) *dacc = 0.0;
}

// -------- finalize: gather + LayerNorm + commitment partial ---------------
__global__ __launch_bounds__(256)
void k_finalize(const unsigned long long* __restrict__ am,
                const float* __restrict__ embT, const float* __restrict__ zf,
                const float* __restrict__ gamma, const float* __restrict__ beta,
                float* __restrict__ out, double* __restrict__ dacc) {
  const int row = blockIdx.x;
  const int tid = threadIdx.x;
  const int lane = tid & 63, w = tid >> 6;
  const int idx = (int)(am[row] & 0xFFFFFFFFull);

  const float4 e4 = *(const float4*)(embT + (size_t)idx * C_ + tid * 4);
  float s1 = e4.x + e4.y + e4.z + e4.w;
  float s2 = e4.x * e4.x + e4.y * e4.y + e4.z * e4.z + e4.w * e4.w;
#pragma unroll
  for (int off = 32; off >= 1; off >>= 1) {
    s1 += __shfl_xor(s1, off, 64);
    s2 += __shfl_xor(s2, off, 64);
  }
  __shared__ float r1[4], r2[4], rd[4];
  if (lane == 0) { r1[w] = s1; r2[w] = s2; }
  __syncthreads();
  const float S1 = r1[0] + r1[1] + r1[2] + r1[3];
  const float S2 = r2[0] + r2[1] + r2[2] + r2[3];
  const float mu = S1 * (1.f / C_);
  const float var = S2 * (1.f / C_) - mu * mu;
  const float inv = 1.f / sqrtf(var + 1e-5f);

  const float4 z4 = *(const float4*)(zf + (size_t)row * C_ + tid * 4);
  const float4 g4 = *(const float4*)(gamma + tid * 4);
  const float4 b4 = *(const float4*)(beta + tid * 4);
  float4 o4;
  o4.x = (e4.x - mu) * inv * g4.x + b4.x;
  o4.y = (e4.y - mu) * inv * g4.y + b4.y;
  o4.z = (e4.z - mu) * inv * g4.z + b4.z;
  o4.w = (e4.w - mu) * inv * g4.w + b4.w;
  *(float4*)(out + (size_t)row * C_ + tid * 4) = o4;

  const float dx = e4.x - z4.x, dy = e4.y - z4.y, dz = e4.z - z4.z, dw = e4.w - z4.w;
  float d = dx * dx + dy * dy + dz * dz + dw * dw;
#pragma unroll
  for (int off = 32; off >= 1; off >>= 1) d += __shfl_xor(d, off, 64);
  __syncthreads();
  if (lane == 0) rd[w] = d;
  __syncthreads();
  if (tid == 0) atomicAdd(dacc, (double)(rd[0] + rd[1] + rd[2] + rd[3]));
}

__global__ void k_wdiff(const double* __restrict__ dacc, float* __restrict__ out) {
  out[(size_t)B_ * C_] = (float)(0.01 * (*dacc) / ((double)B_ * (double)C_));
}

// ---------------------------------------------------------------------------
extern "C" void kernel_launch(void* const* d_in, const int* in_sizes, int n_in,
                              void* d_out, int out_size, void* d_ws, size_t ws_size,
                              hipStream_t stream) {
  const float* x     = (const float*)d_in[0];
  const float* W1    = (const float*)d_in[1];
  const float* b1    = (const float*)d_in[2];
  const float* W2    = (const float*)d_in[3];
  const float* b2    = (const float*)d_in[4];
  const float* gamma = (const float*)d_in[5];
  const float* beta  = (const float*)d_in[6];
  const float* embed = (const float*)d_in[7];
  float* out = (float*)d_out;

  char* ws = (char*)d_ws;
  const size_t MB64 = 67108864ull;  // 8192*4096*2
  u16* xh  = (u16*)(ws);
  u16* xl  = (u16*)(ws + MB64);
  u16* w1h = (u16*)(ws + 2 * MB64);
  u16* w1l = (u16*)(ws + 2 * MB64 + 33554432ull);
  u16* hh  = (u16*)(ws + 3 * MB64);
  u16* hl  = (u16*)(ws + 4 * MB64);
  u16* w2h = (u16*)(ws);
  u16* w2l = (u16*)(ws + 8388608ull);
  float* zf = (float*)(ws + 16777216ull);
  u16* zh  = (u16*)(ws + MB64);
  u16* zl  = (u16*)(ws + MB64 + 16777216ull);
  float* norms = (float*)(ws + MB64 + 33554432ull);
  unsigned long long* am = (unsigned long long*)(ws + MB64 + 33554432ull + 65536ull);
  double* dacc = (double*)(ws + MB64 + 33554432ull + 131072ull);
  float* embT = (float*)(ws + 2 * MB64);
  u16* eh  = (u16*)(ws + 2 * MB64 + 33554432ull);
  u16* el  = (u16*)(ws + 2 * MB64 + 50331648ull);

  // 1. split x -> xh/xl
  k_split<<<2048, 256, 0, stream>>>((const float4*)x, (size_t)B_ * D_ / 4, xh, xl);
  // 2. W1 [D][4C] -> W1T hi/lo [4C][D]
  k_tsplit<false><<<dim3(C4_ / 32, D_ / 32), dim3(32, 8), 0, stream>>>(W1, D_, C4_, w1h, w1l, nullptr);
  // 3. GEMM1 (+bias+SiLU+split)
  k_gemm1<<<(B_ / BM) * (C4_ / BN), 256, 0, stream>>>(xh, xl, w1h, w1l, b1, hh, hl);
  // 4. W2 [4C][C] -> W2T hi/lo [C][4C]  (region A is free now)
  k_tsplit<false><<<dim3(C_ / 32, C4_ / 32), dim3(32, 8), 0, stream>>>(W2, C4_, C_, w2h, w2l, nullptr);
  // 5. GEMM2 (+bias, write z f32 + hi/lo)
  k_gemm2<<<(B_ / BM) * (C_ / BN), 256, 0, stream>>>(hh, hl, w2h, w2l, b2, zf, zh, zl);
  // 6. embed [C][K] -> embT f32 + hi/lo [K][C]  (regions C/D free now)
  k_tsplit<true><<<dim3(K_ / 32, C_ / 32), dim3(32, 8), 0, stream>>>(embed, C_, K_, eh, el, embT);
  // 7. codebook column norms (f64 accumulate)
  k_norms<<<K_ / 256, 256, 0, stream>>>(embed, norms);
  // 8. init argmin keys + diff accumulator
  k_init<<<B_ / 256, 256, 0, stream>>>(am, dacc);
  // 9. GEMM3 + fused argmin
  k_gemm3<<<(B_ / BM) * (K_ / BN), 256, 0, stream>>>(zh, zl, eh, el, norms, am);
  // 10. gather + LayerNorm + commitment partial sums
  k_finalize<<<B_, 256, 0, stream>>>(am, embT, zf, gamma, beta, out, dacc);
  // 11. scalar diff output
  k_wdiff<<<1, 1, 0, stream>>>(dacc, out);
}